// Round 8
// baseline (60.666 us; speedup 1.0000x reference)
//
#include <hip/hip_runtime.h>
#include <math.h>

// DTW loss: B=64, N=512, D=2, L1. Wave64 per batch, lane j owns cols [8j,8j+8).
// Round-8: 2-ROW MACRO-STEPS. Model (fits R2-R7): lone-wave step =
// max(chain_ops x ~11.5cy, instr x ~4.3cy). R7 was chain-bound: 17-op cycle
// (dpp + 8x(min3+add)) = 208cy/row. A 2-row macro has the SAME ~17-op cycle
// but advances 2 rows -> ~105cy/row. Lane j, macro m: rows i0=2(m-j), i0+1.
//   leftA = dpp(a[7] prev macro)   [D[i0][8j-1]]
//   leftB = dpp(b[7] prev macro)   [D[i0+1][8j-1]]
//   dgA   = leftB of prev macro    [D[i0-1][8j-1]]
//   a[c] = costA + min3(pb[c], pb[c-1]|dgA, a[c-1]|leftA)
//   b[c] = costB + min3(a[c],  a[c-1]|leftA, b[c-1]|leftB)
// One ds_read_b128 per macro (row pair = one float4). No guards: INF algebra
// makes ramp commits harmless; drain garbage provably never consumed.

typedef float f32x2 __attribute__((ext_vector_type(2)));
typedef float f32x4 __attribute__((ext_vector_type(4)));

constexpr int NSEQ  = 512;
constexpr int BATCH = 64;
constexpr int LANES = 64;
constexpr int P     = 8;
constexpr int FRONT = 63;     // front pad in float4 rows-pairs (m-j >= -63)
constexpr int XS4N  = 384;    // 63 front + 256 valid + 65 back (prefetch to 383)

__device__ __forceinline__ float dpp_shr1_inf(float v) {
    // lane i <- lane i-1; lane 0 <- +inf (bound_ctrl=false)
    int r = __builtin_amdgcn_update_dpp(0x7F800000, __float_as_int(v),
                                        0x138, 0xF, 0xF, false);
    return __int_as_float(r);
}
__device__ __forceinline__ f32x2 pk_add(f32x2 a, f32x2 b) {
    f32x2 d;
    asm("v_pk_add_f32 %0, %1, %2" : "=v"(d) : "v"(a), "v"(b));
    return d;
}

__global__ __launch_bounds__(LANES) void dtw_fused(
    const float* __restrict__ pred,    // (B, N, 2) rows (x)
    const float* __restrict__ target,  // (B, N, 2) cols (y)
    float* __restrict__ out,
    float* __restrict__ ws)            // [0..63] per_batch, [64] flag
{
    const int b = blockIdx.x;
    const int j = threadIdx.x;

    __shared__ f32x4 xs4[XS4N];        // one entry = one ROW PAIR (2x float2)

    // stage: pred[b] = 256 float4 row-pairs; zero the pads (determinism)
    const f32x4* pred4 = reinterpret_cast<const f32x4*>(pred) + b * (NSEQ / 2);
    #pragma unroll
    for (int t = 0; t < 4; ++t)
        xs4[FRONT + t * LANES + j] = pred4[t * LANES + j];
    if (j < FRONT) xs4[j] = f32x4{0.f, 0.f, 0.f, 0.f};
    xs4[FRONT + 256 + j] = f32x4{0.f, 0.f, 0.f, 0.f};        // 319..382
    if (j == 0) xs4[383] = f32x4{0.f, 0.f, 0.f, 0.f};

    f32x2 nY[P];
    #pragma unroll
    for (int c = 0; c < P; ++c) {
        const f32x2 y = reinterpret_cast<const f32x2*>(target)[b * NSEQ + j * P + c];
        nY[c].x = -y.x; nY[c].y = -y.y;
    }
    __syncthreads();   // only barrier

    const float INF = __builtin_inff();
    float p[P], q[P], aA[P], aB[P];
    float dg = INF;    // dgA for next macro = leftB of previous macro

    // ---- peeled macro 0: rows 0,1. Lane 0 real (leftA=0 for a[0] only,
    // diag for b[0] = INF); other lanes all-INF via identities. ----
    f32x4 x0 = xs4[FRONT - j];
    f32x4 xc1 = xs4[FRONT + 1 - j];
    f32x4 xc2 = xs4[FRONT + 2 - j];
    {
        const f32x2 xa = {x0.x, x0.y}, xb = {x0.z, x0.w};
        const float lA0 = (j == 0) ? 0.0f : INF;
        { const f32x2 d = pk_add(xa, nY[0]); aA[0] = fabsf(d.x) + fabsf(d.y) + lA0; }
        #pragma unroll
        for (int c = 1; c < P; ++c) {
            const f32x2 d = pk_add(xa, nY[c]);
            aA[c] = fabsf(d.x) + fabsf(d.y) + aA[c - 1];        // row-0 cumsum
        }
        { const f32x2 d = pk_add(xb, nY[0]); p[0] = fabsf(d.x) + fabsf(d.y) + aA[0]; }
        #pragma unroll
        for (int c = 1; c < P; ++c) {
            const f32x2 d = pk_add(xb, nY[c]);
            p[c] = fabsf(d.x) + fabsf(d.y)
                 + fminf(fminf(aA[c], aA[c - 1]), p[c - 1]);
        }
    }

    // macro: reads prev-b pb[], prev-a ain[]; writes ob[], aout[]
    auto macro = [&](const float (&pb)[P], float (&ob)[P],
                     const float (&ain)[P], float (&aout)[P], f32x4 x4) {
        const float lA = dpp_shr1_inf(ain[P - 1]);
        const float lB = dpp_shr1_inf(pb[P - 1]);
        const f32x2 xa = {x4.x, x4.y}, xb = {x4.z, x4.w};
        { const f32x2 d = pk_add(xa, nY[0]);
          aout[0] = fabsf(d.x) + fabsf(d.y) + fminf(fminf(pb[0], dg), lA); }
        #pragma unroll
        for (int c = 1; c < P; ++c) {
            const f32x2 d = pk_add(xa, nY[c]);
            aout[c] = fabsf(d.x) + fabsf(d.y)
                    + fminf(fminf(pb[c], pb[c - 1]), aout[c - 1]);
        }
        { const f32x2 d = pk_add(xb, nY[0]);
          ob[0] = fabsf(d.x) + fabsf(d.y) + fminf(fminf(aout[0], lA), lB); }
        #pragma unroll
        for (int c = 1; c < P; ++c) {
            const f32x2 d = pk_add(xb, nY[c]);
            ob[c] = fabsf(d.x) + fabsf(d.y)
                  + fminf(fminf(aout[c], aout[c - 1]), ob[c - 1]);
        }
        dg = lB;
    };

    // 159 pairs cover macros m = 1..318; 1-pair-deep x prefetch.
    #pragma unroll 2
    for (int mm = 0; mm < 159; ++mm) {
        const int m1 = 1 + 2 * mm;
        const f32x4 xn1 = xs4[FRONT + m1 + 2 - j];
        const f32x4 xn2 = xs4[FRONT + m1 + 3 - j];
        macro(p, q, aA, aB, xc1);    // macro m1
        macro(q, p, aB, aA, xc2);    // macro m1+1
        xc1 = xn1; xc2 = xn2;
    }

    // ---- fused mean reduction (last block to finish) ----
    float* per_batch = ws;
    unsigned* flag = reinterpret_cast<unsigned*>(ws + BATCH);
    if (j == LANES - 1) per_batch[b] = p[P - 1];   // D[511][511]
    __threadfence();
    unsigned old = 0;
    if (j == 0) old = atomicAdd(flag, 1u);
    old = __shfl(old, 0);
    if (old == BATCH - 1) {
        __threadfence();
        float v = per_batch[j];
        #pragma unroll
        for (int off = 32; off >= 1; off >>= 1) v += __shfl_down(v, off);
        if (j == 0) out[0] = v * (1.0f / BATCH);
    }
}

extern "C" void kernel_launch(void* const* d_in, const int* in_sizes, int n_in,
                              void* d_out, int out_size, void* d_ws, size_t ws_size,
                              hipStream_t stream) {
    const float* pred   = (const float*)d_in[0];
    const float* target = (const float*)d_in[1];
    float* out = (float*)d_out;
    float* ws  = (float*)d_ws;

    hipMemsetAsync((char*)d_ws + BATCH * sizeof(float), 0, sizeof(unsigned), stream);
    dtw_fused<<<BATCH, LANES, 0, stream>>>(pred, target, out, ws);
}